// Round 4
// baseline (3088.930 us; speedup 1.0000x reference)
//
#include <hip/hip_runtime.h>
#include <hip/hip_bf16.h>
#include <cstdint>
#include <cstddef>

#define DEVI __device__ __forceinline__

typedef __bf16 v8bf __attribute__((ext_vector_type(8)));
typedef float  v4f  __attribute__((ext_vector_type(4)));
using u16 = unsigned short;

// problem dims
constexpr int kB = 4096, kT = 16, kH = 256, kF = 256, kZ = 128, kP = 10, kPrev = 5;
constexpr int kRows = 32;   // rows per block; grid = 4096/32 = 128

// ---- workspace layout (bf16 elements): transposed weights ONLY (~2.82 MB) ----
// WT layout: WT[n][k] (row n = output col, wtK = K of that matmul)
constexpr size_t OFF_WzT = 0;                                  // Wz: n=1024, K=128
constexpr size_t OFF_WhT = OFF_WzT + (size_t)1024 * 128;       // Wh: n=1024, K=256
constexpr size_t OFF_WyT = OFF_WhT + (size_t)1024 * 256;       // Wy: n=1024, K=256
constexpr size_t OFF_UT  = OFF_WyT + (size_t)1024 * 256;       // U : n=1024, K=256
constexpr size_t OFF_W1T = OFF_UT  + (size_t)1024 * 256;       // W1: n=256, K=256
constexpr size_t OFF_W2T = OFF_W1T + (size_t)256 * 256;
constexpr size_t OFF_W3T = OFF_W2T + (size_t)256 * 256;
constexpr size_t OFF_W4T = OFF_W3T + (size_t)256 * 256;        // W4: n=128, K=1024
constexpr size_t OFF_W5T = OFF_W4T + (size_t)128 * 1024;       // W5: n=128, K=128
constexpr size_t OFF_W6T = OFF_W5T + (size_t)128 * 128;
constexpr size_t OFF_W7T = OFF_W6T + (size_t)128 * 128;        // W7: n=128, K=768
constexpr size_t OFF_W8T = OFF_W7T + (size_t)128 * 768;
constexpr size_t OFF_W9T = OFF_W8T + (size_t)128 * 128;
constexpr size_t OFF_WEND= OFF_W9T + (size_t)128 * 128;        // total weight elems

// ---- output layout (elements, FLOAT32 — reference output dtype) ----
constexpr size_t O_YS   = 0;
constexpr size_t O_MPO  = O_YS   + (size_t)kB * kP * kF;
constexpr size_t O_LVPO = O_MPO  + (size_t)kB * kP * kZ;
constexpr size_t O_MPR  = O_LVPO + (size_t)kB * kP * kZ;
constexpr size_t O_LVPR = O_MPR  + (size_t)kB * kP * kZ;
constexpr size_t O_ZPO  = O_LVPR + (size_t)kB * kP * kZ;
constexpr size_t O_ZPR  = O_ZPO  + (size_t)kP * kB * kZ;
constexpr size_t O_PROB = O_ZPR  + (size_t)kP * kB * kZ;

DEVI float bf2f(u16 u) { return __uint_as_float(((unsigned)u) << 16); }
DEVI u16 f2bf(float f) {
    unsigned x = __float_as_uint(f);
    return (u16)((x + 0x7fffu + ((x >> 16) & 1u)) >> 16);   // RNE
}
DEVI unsigned pk2(float lo, float hi) { return (unsigned)f2bf(lo) | ((unsigned)f2bf(hi) << 16); }
DEVI float upk(unsigned u, int hi) { return __uint_as_float(hi ? (u & 0xffff0000u) : (u << 16)); }
DEVI float sigf(float x) { x = fminf(fmaxf(x, -40.f), 40.f); return 1.f / (1.f + __expf(-x)); }
DEVI float tanhf_(float x) {
    x = fminf(fmaxf(x, -15.f), 15.f);
    float e = __expf(2.f * x);
    return (e - 1.f) / (e + 1.f);
}
DEVI v8bf ld8(const u16* p) { return *(const v8bf*)p; }

template <int NTL>
DEVI void zacc(v4f (&a)[NTL][2]) {
#pragma unroll
    for (int t = 0; t < NTL; ++t) { a[t][0] = v4f{0, 0, 0, 0}; a[t][1] = v4f{0, 0, 0, 0}; }
}

// C[m][n] += A[m][k] * W[k][n], A in LDS row-major [32][K+pad] (bf16), W
// transposed bf16 in global: WT row n has wtK elems, cols [wtOff, wtOff+K).
// A frag: lane holds A[m=lane&15][k=quad*8+j]; B frag: B[k=quad*8+j][n=lane&15];
// C/D: col=lane&15, row=quad*4+reg.  (16x16x32 bf16 MFMA, guide-verified.)
template <int K, int NTL, class NFN>
DEVI void gemm_acc(v4f (&acc)[NTL][2], const u16* A, int astr,
                   const u16* __restrict__ WT, int wtK, int wtOff,
                   NFN nf, int ln, int q) {
    const u16* A0 = A + ln * astr + q * 8;
#pragma unroll
    for (int k0 = 0; k0 < K; k0 += 32) {
        v8bf a0 = ld8(A0 + k0);
        v8bf a1 = ld8(A0 + 16 * astr + k0);
#pragma unroll
        for (int t = 0; t < NTL; ++t) {
            const u16* bp = WT + (size_t)(nf(t) + ln) * wtK + (size_t)(wtOff + k0 + q * 8);
            v8bf b = ld8(bp);
            acc[t][0] = __builtin_amdgcn_mfma_f32_16x16x32_bf16(a0, b, acc[t][0], 0, 0, 0);
            acc[t][1] = __builtin_amdgcn_mfma_f32_16x16x32_bf16(a1, b, acc[t][1], 0, 0, 0);
        }
    }
}

// relu epilogue -> LDS (bf16)
template <int NTL, class NFN>
DEVI void epi_relu(v4f (&acc)[NTL][2], const float* __restrict__ bias,
                   u16* s_dst, int dstr, NFN nf, int ln, int q) {
#pragma unroll
    for (int t = 0; t < NTL; ++t)
#pragma unroll
        for (int m2 = 0; m2 < 2; ++m2)
#pragma unroll
            for (int r = 0; r < 4; ++r) {
                int rl = m2 * 16 + q * 4 + r, n = nf(t) + ln;
                s_dst[rl * dstr + n] = f2bf(fmaxf(acc[t][m2][r] + bias[n], 0.f));
            }
}

// ---------------- weight transpose: f32 W[k][n] -> bf16 WT[n][k] ----------------
__global__ void transpose_w(const float* __restrict__ Wl, const float* __restrict__ U,
                            const float* __restrict__ W1, const float* __restrict__ W2,
                            const float* __restrict__ W3, const float* __restrict__ W4,
                            const float* __restrict__ W5, const float* __restrict__ W6,
                            const float* __restrict__ W7, const float* __restrict__ W8,
                            const float* __restrict__ W9, u16* __restrict__ ws) {
    size_t e = (size_t)blockIdx.x * blockDim.x + threadIdx.x;
    auto tp = [&](size_t eo, size_t dst, const float* src, int K, int srcN, int rowOff) {
        size_t n = eo / (size_t)K;
        size_t k = eo - n * (size_t)K;
        ws[dst + eo] = f2bf(src[(size_t)(rowOff + k) * srcN + n]);
    };
    // W_lstm is (640, 1024): rows 0..127 z, 128..383 h_i, 384..639 y_prev
    if      (e < OFF_WhT) tp(e - OFF_WzT, OFF_WzT, Wl, 128, 1024, 0);
    else if (e < OFF_WyT) tp(e - OFF_WhT, OFF_WhT, Wl, 256, 1024, 128);
    else if (e < OFF_UT)  tp(e - OFF_WyT, OFF_WyT, Wl, 256, 1024, 384);
    else if (e < OFF_W1T) tp(e - OFF_UT,  OFF_UT,  U,  256, 1024, 0);
    else if (e < OFF_W2T) tp(e - OFF_W1T, OFF_W1T, W1, 256, 256, 0);
    else if (e < OFF_W3T) tp(e - OFF_W2T, OFF_W2T, W2, 256, 256, 0);
    else if (e < OFF_W4T) tp(e - OFF_W3T, OFF_W3T, W3, 256, 256, 0);
    else if (e < OFF_W5T) tp(e - OFF_W4T, OFF_W4T, W4, 1024, 128, 0);
    else if (e < OFF_W6T) tp(e - OFF_W5T, OFF_W5T, W5, 128, 128, 0);
    else if (e < OFF_W7T) tp(e - OFF_W6T, OFF_W6T, W6, 128, 128, 0);
    else if (e < OFF_W8T) tp(e - OFF_W7T, OFF_W7T, W7, 768, 128, 0);
    else if (e < OFF_W9T) tp(e - OFF_W8T, OFF_W8T, W8, 128, 128, 0);
    else if (e < OFF_WEND)tp(e - OFF_W9T, OFF_W9T, W9, 128, 128, 0);
}

// ---------------- fused recurrent kernel: 32 rows/block, 10 steps ----------------
__global__ __launch_bounds__(256, 1) void fused_vrnn(
    const float* __restrict__ g_hi, const float* __restrict__ g_t,
    const float* __restrict__ g_npo, const float* __restrict__ g_npr,
    const float* __restrict__ b_lstm, const float* __restrict__ b1,
    const float* __restrict__ b2, const float* __restrict__ b3,
    const float* __restrict__ b4, const float* __restrict__ b5,
    const float* __restrict__ b6, const float* __restrict__ b7,
    const float* __restrict__ b8, const float* __restrict__ b9,
    const float* __restrict__ g_alpha, const float* __restrict__ g_beta,
    const float* __restrict__ g_base,
    const u16* __restrict__ ws, float* __restrict__ out) {
    // LDS activations: +8 bf16 pad per row (2-way bank alias = free)
    __shared__ __align__(16) u16 s_h[kRows][kH + 8];
    __shared__ __align__(16) u16 s_zj[kRows][kZ + 8];
    __shared__ __align__(16) u16 s_yp[2][kRows][kF + 8];
    __shared__ __align__(16) u16 s_hraw[kRows][kH + 8];
    __shared__ __align__(16) u16 s_t1[kRows][kF + 8];
    __shared__ __align__(16) u16 s_hz[kRows][kZ + 8];
    __shared__ __align__(16) u16 s_hzp[kRows][kZ + 8];
    __shared__ float s_lam[kP][kRows];

    const int tid = threadIdx.x;
    const int w = tid >> 6, lane = tid & 63, ln = lane & 15, q = lane >> 4;
    const int r0 = blockIdx.x * kRows;

    // zero recurrent state, stage h_i (f32 -> bf16) into s_hraw
    for (int i = tid; i < kRows * (kH + 8); i += 256) (&s_h[0][0])[i] = 0;
    for (int i = tid; i < kRows * (kZ + 8); i += 256) (&s_zj[0][0])[i] = 0;
    for (int i = tid; i < 2 * kRows * (kF + 8); i += 256) (&s_yp[0][0][0])[i] = 0;
    for (int i = tid; i < kRows * kH; i += 256) {
        int r = i >> 8, c = i & (kH - 1);
        s_hraw[r][c] = f2bf(g_hi[(size_t)(r0 + r) * kH + c]);
    }

    // Hawkes lam/prob per row (tiny; threads 0..31, one row each), f32 exact
    if (tid < kRows) {
        const float alpha = g_alpha[0], beta = g_beta[0], base = g_base[0];
        float tv[kT];
#pragma unroll
        for (int i = 0; i < kT; ++i) tv[i] = g_t[(size_t)(r0 + tid) * kT + i];
#pragma unroll 1
        for (int j = 0; j < kP; ++j) {
            int cti = kPrev + j;
            float ct = tv[cti], last = tv[cti - 1];
            float tk = 0.f, td3 = 0.f;
            for (int i = 0; i < cti; ++i) {
                tk += __expf(beta * (tv[i] - ct));
                td3 += __expf(beta * (tv[i] - last));
            }
            float lam = base + alpha * tk;
            float prob = lam * __expf((last - ct) * base + (alpha / beta) * (tk - td3));
            s_lam[j][tid] = lam;
            out[O_PROB + (size_t)j * kB + (size_t)(r0 + tid)] = prob;
        }
    }
    __syncthreads();

    auto nfg = [&](int t) { return ((t >> 2) << 8) + (w << 6) + ((t & 3) << 4); }; // gates: 4 groups x 256
    auto nf4 = [&](int t) { return (w << 6) + (t << 4); };                          // N=256
    auto nf2 = [&](int t) { return (w << 5) + (t << 4); };                          // N=128

    // ---- step-invariant h_i partials, kept in REGISTERS (packed bf16 pairs).
    // Slot (t,m2,r) <-> logical (row=m2*16+q*4+r, col=nf(t)+ln) — same slot is
    // consumed by the same thread in the step loop, so no memory round-trip.
    unsigned ghi_p[16][2][2];   // h_i @ W_lstm[h_i rows]  (cols 0..1023 via nfg)
    unsigned h4i_p[2][2][2];    // h_i @ W4[0:256]         (cols 0..127 via nf2)
    unsigned h7i_p[2][2][2];    // h_i @ W7[0:256]
    {
        v4f acc[16][2]; zacc(acc);
        gemm_acc<256, 16>(acc, &s_hraw[0][0], kH + 8, ws + OFF_WhT, 256, 0, nfg, ln, q);
#pragma unroll
        for (int t = 0; t < 16; ++t)
#pragma unroll
            for (int m2 = 0; m2 < 2; ++m2)
#pragma unroll
                for (int rp = 0; rp < 2; ++rp)
                    ghi_p[t][m2][rp] = pk2(acc[t][m2][2 * rp], acc[t][m2][2 * rp + 1]);
    }
    {
        v4f acc[2][2]; zacc(acc);
        gemm_acc<256, 2>(acc, &s_hraw[0][0], kH + 8, ws + OFF_W4T, 1024, 0, nf2, ln, q);
#pragma unroll
        for (int t = 0; t < 2; ++t)
#pragma unroll
            for (int m2 = 0; m2 < 2; ++m2)
#pragma unroll
                for (int rp = 0; rp < 2; ++rp)
                    h4i_p[t][m2][rp] = pk2(acc[t][m2][2 * rp], acc[t][m2][2 * rp + 1]);
    }
    {
        v4f acc[2][2]; zacc(acc);
        gemm_acc<256, 2>(acc, &s_hraw[0][0], kH + 8, ws + OFF_W7T, 768, 0, nf2, ln, q);
#pragma unroll
        for (int t = 0; t < 2; ++t)
#pragma unroll
            for (int m2 = 0; m2 < 2; ++m2)
#pragma unroll
                for (int rp = 0; rp < 2; ++rp)
                    h7i_p[t][m2][rp] = pk2(acc[t][m2][2 * rp], acc[t][m2][2 * rp + 1]);
    }
    __syncthreads();

    // LSTM cell state in registers: c_st[s][m2][r] <-> col w*64+s*16+ln, row m2*16+q*4+r
    float c_st[4][2][4];
#pragma unroll
    for (int s = 0; s < 4; ++s)
#pragma unroll
        for (int m2 = 0; m2 < 2; ++m2)
#pragma unroll
            for (int r = 0; r < 4; ++r) c_st[s][m2][r] = 0.f;

#pragma unroll 1
    for (int j = 0; j < kP; ++j) {
        const int cur = j & 1, nxt = cur ^ 1;

        // ---- LSTM gates: zj@Wz + y_prev@Wy + h@U (+ ghi + b) ----
        {
            v4f acc[16][2]; zacc(acc);
            gemm_acc<128, 16>(acc, &s_zj[0][0], kZ + 8, ws + OFF_WzT, 128, 0, nfg, ln, q);
            gemm_acc<256, 16>(acc, &s_yp[cur][0][0], kF + 8, ws + OFF_WyT, 256, 0, nfg, ln, q);
            gemm_acc<256, 16>(acc, &s_h[0][0], kH + 8, ws + OFF_UT, 256, 0, nfg, ln, q);
            __syncthreads();  // all waves done reading s_h before overwriting it
#pragma unroll
            for (int s = 0; s < 4; ++s)
#pragma unroll
                for (int m2 = 0; m2 < 2; ++m2)
#pragma unroll
                    for (int r = 0; r < 4; ++r) {
                        const int rl = m2 * 16 + q * 4 + r;
                        const int nc = (w << 6) + (s << 4) + ln;
                        float gi = acc[s][m2][r]      + upk(ghi_p[s][m2][r >> 1], r & 1)      + b_lstm[0   + nc];
                        float gf = acc[4 + s][m2][r]  + upk(ghi_p[4 + s][m2][r >> 1], r & 1)  + b_lstm[256 + nc];
                        float gg = acc[8 + s][m2][r]  + upk(ghi_p[8 + s][m2][r >> 1], r & 1)  + b_lstm[512 + nc];
                        float go = acc[12 + s][m2][r] + upk(ghi_p[12 + s][m2][r >> 1], r & 1) + b_lstm[768 + nc];
                        float cs = c_st[s][m2][r];
                        cs = sigf(gf) * cs + sigf(gi) * tanhf_(gg);
                        float hr = sigf(go) * tanhf_(cs);
                        c_st[s][m2][r] = cs;
                        float lamv = s_lam[j][rl];
                        s_hraw[rl][nc] = f2bf(hr);
                        s_h[rl][nc] = f2bf(lamv * hr);
                    }
        }
        __syncthreads();

        // ---- y = relu(relu(relu(hraw@W1)@W2)@W3) ----
        {
            v4f a[4][2]; zacc(a);
            gemm_acc<256, 4>(a, &s_hraw[0][0], kH + 8, ws + OFF_W1T, 256, 0, nf4, ln, q);
            epi_relu<4>(a, b1, &s_t1[0][0], kF + 8, nf4, ln, q);
        }
        __syncthreads();
        {
            v4f a[4][2]; zacc(a);
            gemm_acc<256, 4>(a, &s_t1[0][0], kF + 8, ws + OFF_W2T, 256, 0, nf4, ln, q);
            __syncthreads();  // in-place on s_t1
            epi_relu<4>(a, b2, &s_t1[0][0], kF + 8, nf4, ln, q);
        }
        __syncthreads();
        {
            v4f a[4][2]; zacc(a);
            gemm_acc<256, 4>(a, &s_t1[0][0], kF + 8, ws + OFF_W3T, 256, 0, nf4, ln, q);
#pragma unroll
            for (int t = 0; t < 4; ++t)
#pragma unroll
                for (int m2 = 0; m2 < 2; ++m2)
#pragma unroll
                    for (int r = 0; r < 4; ++r) {
                        int rl = m2 * 16 + q * 4 + r, n = nf4(t) + ln;
                        size_t row = (size_t)(r0 + rl);
                        float yv = fmaxf(a[t][m2][r] + b3[n], 0.f);
                        s_yp[nxt][rl][n] = f2bf(yv);                       // y (next y_prev)
                        out[O_YS + (row * kP + j) * kF + n] = yv;          // ys output (f32)
                    }
        }
        __syncthreads();

        // ---- hz = relu([h_i, hraw, y, y_prev]@W4 + b4) ----
        {
            v4f a[2][2]; zacc(a);
            gemm_acc<256, 2>(a, &s_hraw[0][0], kH + 8, ws + OFF_W4T, 1024, 256, nf2, ln, q);
            gemm_acc<256, 2>(a, &s_yp[nxt][0][0], kF + 8, ws + OFF_W4T, 1024, 512, nf2, ln, q);
            gemm_acc<256, 2>(a, &s_yp[cur][0][0], kF + 8, ws + OFF_W4T, 1024, 768, nf2, ln, q);
#pragma unroll
            for (int t = 0; t < 2; ++t)
#pragma unroll
                for (int m2 = 0; m2 < 2; ++m2)
#pragma unroll
                    for (int r = 0; r < 4; ++r) {
                        int rl = m2 * 16 + q * 4 + r, n = nf2(t) + ln;
                        float v = a[t][m2][r] + upk(h4i_p[t][m2][r >> 1], r & 1) + b4[n];
                        s_hz[rl][n] = f2bf(fmaxf(v, 0.f));
                    }
        }
        __syncthreads();

        // ---- posterior mean/logv, z_j ----
        {
            v4f a5[2][2], a6[2][2]; zacc(a5); zacc(a6);
            gemm_acc<128, 2>(a5, &s_hz[0][0], kZ + 8, ws + OFF_W5T, 128, 0, nf2, ln, q);
            gemm_acc<128, 2>(a6, &s_hz[0][0], kZ + 8, ws + OFF_W6T, 128, 0, nf2, ln, q);
#pragma unroll
            for (int t = 0; t < 2; ++t)
#pragma unroll
                for (int m2 = 0; m2 < 2; ++m2)
#pragma unroll
                    for (int r = 0; r < 4; ++r) {
                        int rl = m2 * 16 + q * 4 + r, n = nf2(t) + ln;
                        size_t row = (size_t)(r0 + rl);
                        float mn = fmaxf(a5[t][m2][r] + b5[n], 0.f);
                        float lv = fmaxf(a6[t][m2][r] + b6[n], 0.f);
                        out[O_MPO + (row * kP + j) * kZ + n] = mn;
                        out[O_LVPO + (row * kP + j) * kZ + n] = lv;
                        float nz = g_npo[((size_t)j * kB + row) * kZ + n];
                        float zj = mn + nz * __expf(0.5f * lv);            // sqrt(exp(lv))
                        s_zj[rl][n] = f2bf(zj);
                        out[O_ZPO + ((size_t)j * kB + row) * kZ + n] = zj;
                    }
        }
        __syncthreads();

        // ---- hz_p = relu([h_i, hraw, y_prev]@W7 + b7) ----
        {
            v4f a[2][2]; zacc(a);
            gemm_acc<256, 2>(a, &s_hraw[0][0], kH + 8, ws + OFF_W7T, 768, 256, nf2, ln, q);
            gemm_acc<256, 2>(a, &s_yp[cur][0][0], kF + 8, ws + OFF_W7T, 768, 512, nf2, ln, q);
#pragma unroll
            for (int t = 0; t < 2; ++t)
#pragma unroll
                for (int m2 = 0; m2 < 2; ++m2)
#pragma unroll
                    for (int r = 0; r < 4; ++r) {
                        int rl = m2 * 16 + q * 4 + r, n = nf2(t) + ln;
                        float v = a[t][m2][r] + upk(h7i_p[t][m2][r >> 1], r & 1) + b7[n];
                        s_hzp[rl][n] = f2bf(fmaxf(v, 0.f));
                    }
        }
        __syncthreads();

        // ---- prior mean/logv, z_p ----
        {
            v4f a8[2][2], a9[2][2]; zacc(a8); zacc(a9);
            gemm_acc<128, 2>(a8, &s_hzp[0][0], kZ + 8, ws + OFF_W8T, 128, 0, nf2, ln, q);
            gemm_acc<128, 2>(a9, &s_hzp[0][0], kZ + 8, ws + OFF_W9T, 128, 0, nf2, ln, q);
#pragma unroll
            for (int t = 0; t < 2; ++t)
#pragma unroll
                for (int m2 = 0; m2 < 2; ++m2)
#pragma unroll
                    for (int r = 0; r < 4; ++r) {
                        int rl = m2 * 16 + q * 4 + r, n = nf2(t) + ln;
                        size_t row = (size_t)(r0 + rl);
                        float mp = fmaxf(a8[t][m2][r] + b8[n], 0.f);
                        float lp = fmaxf(a9[t][m2][r] + b9[n], 0.f);
                        out[O_MPR + (row * kP + j) * kZ + n] = mp;
                        out[O_LVPR + (row * kP + j) * kZ + n] = lp;
                        float nz = g_npr[((size_t)j * kB + row) * kZ + n];
                        out[O_ZPR + ((size_t)j * kB + row) * kZ + n] = mp + nz * __expf(0.5f * lp);
                    }
        }
        __syncthreads();
    }
}

extern "C" void kernel_launch(void* const* d_in, const int* in_sizes, int n_in,
                              void* d_out, int out_size, void* d_ws, size_t ws_size,
                              hipStream_t stream) {
    const float* hi  = (const float*)d_in[0];
    const float* it  = (const float*)d_in[1];
    const float* npo = (const float*)d_in[2];
    const float* npr = (const float*)d_in[3];
    const float* Wl  = (const float*)d_in[4];
    const float* U   = (const float*)d_in[5];
    const float* bl  = (const float*)d_in[6];
    const float* W1  = (const float*)d_in[7];
    const float* b1  = (const float*)d_in[8];
    const float* W2  = (const float*)d_in[9];
    const float* b2  = (const float*)d_in[10];
    const float* W3  = (const float*)d_in[11];
    const float* b3  = (const float*)d_in[12];
    const float* W4  = (const float*)d_in[13];
    const float* b4  = (const float*)d_in[14];
    const float* W5  = (const float*)d_in[15];
    const float* b5  = (const float*)d_in[16];
    const float* W6  = (const float*)d_in[17];
    const float* b6  = (const float*)d_in[18];
    const float* W7  = (const float*)d_in[19];
    const float* b7  = (const float*)d_in[20];
    const float* W8  = (const float*)d_in[21];
    const float* b8  = (const float*)d_in[22];
    const float* W9  = (const float*)d_in[23];
    const float* b9  = (const float*)d_in[24];
    const float* al  = (const float*)d_in[25];
    const float* be  = (const float*)d_in[26];
    const float* ba  = (const float*)d_in[27];
    u16* ws   = (u16*)d_ws;
    float* out = (float*)d_out;

    const unsigned tblocks = (unsigned)((OFF_WEND + 255) / 256);
    transpose_w<<<dim3(tblocks), dim3(256), 0, stream>>>(Wl, U, W1, W2, W3, W4, W5, W6, W7, W8, W9, ws);
    fused_vrnn<<<dim3(kB / kRows), dim3(256), 0, stream>>>(
        hi, it, npo, npr, bl, b1, b2, b3, b4, b5, b6, b7, b8, b9, al, be, ba, ws, out);
}